// Round 8
// baseline (516.360 us; speedup 1.0000x reference)
//
#include <hip/hip_runtime.h>
#include <hip/hip_bf16.h>

// v9: v8's verified fused structure at DOUBLE occupancy.
//  v8 post-mortem: traffic clean (F166/W315) but dispatch 227 us with VALUBusy 13%,
//  MfmaUtil 0.7%, HBM 27% -> latency-bound at 2 blocks/CU (LDS 75776 caps 16
//  waves/CU). Fix: shrink block to o-QUARTER (32 o) + 8-v x' chunks:
//    LDS = 5*[32o][64c] planes (20480) + [8v][16np][64c] x' (16384) + statl (2048)
//        = 38912 B -> 4 blocks/CU; grid 1024 = exactly 4/CU, all resident.
//  __launch_bounds__(512, 8) forces VGPR<=64 (v8 fit 64 with MORE per-wave state)
//  -> 8 waves/SIMD guaranteed -> spin barrier (1024) cannot deadlock.
//  Per-thread VALU work unchanged (same unpack/synth totals, redistributed:
//  8 chunks x 1 o-tile x 2 vj  vs  4 chunks x 2 o-tiles x 4 vj).
//  Cost: x read by 4 o-quarter blocks (raw 4x) -- 67 MB working set is L3-resident.
//  Fusion mechanics (spin barrier, atomic-read phase 2, own-slice phase 3) verbatim
//  from v8 (passed, absmax 0.031).

typedef __bf16 bf16x8 __attribute__((ext_vector_type(8)));
typedef float f32x4 __attribute__((ext_vector_type(4)));

__device__ __forceinline__ unsigned pack2(float a, float b) {
    __hip_bfloat162 h = __float22bfloat162_rn(make_float2(a, b));
    return *reinterpret_cast<unsigned*>(&h);
}
__device__ __forceinline__ void unpack8(uint4 u, float* f) {
    f[0] = __uint_as_float(u.x << 16); f[1] = __uint_as_float(u.x & 0xffff0000u);
    f[2] = __uint_as_float(u.y << 16); f[3] = __uint_as_float(u.y & 0xffff0000u);
    f[4] = __uint_as_float(u.z << 16); f[5] = __uint_as_float(u.z & 0xffff0000u);
    f[6] = __uint_as_float(u.w << 16); f[7] = __uint_as_float(u.w & 0xffff0000u);
}

__global__ __launch_bounds__(512, 8) void conv_bn_fused(
    const float* __restrict__ xr, const float* __restrict__ xi,
    const float* __restrict__ filt, float* __restrict__ out,
    float* __restrict__ gstats, unsigned* __restrict__ done,
    const float* __restrict__ gr, const float* __restrict__ br,
    const float* __restrict__ gi, const float* __restrict__ bi)
{
    __shared__ __align__(16) unsigned short pqT[5 * 2048];    // 20480 B: [32 o][64 c] x5
    __shared__ __align__(16) unsigned short xsh[8 * 16 * 64]; // 16384 B: [8 v][16 np][64 c]
    __shared__ __align__(16) float statl[512];                // 2048 B

    const int t = threadIdx.x;
    const int gid = blockIdx.x;          // 1024 blocks
    const int oq = gid >> 8;             // o-quarter 0..3
    const int u  = (gid & 255) >> 1;     // 0..127
    const int vh = gid & 1;              // v-half
    const int obase = oq << 5;
    const int vbase0 = vh << 6;

    unsigned* pq32 = (unsigned*)pqT;
    unsigned* xs32 = (unsigned*)xsh;

    // ---- stage P/Q planes for (u, o-quarter): once per block
    const float au = 6.28318530717958647692f * (float)u / 128.0f;
    float su1, cu1, su2, cu2;
    __sincosf(au, &su1, &cu1);
    __sincosf(2.0f * au, &su2, &cu2);

    #pragma unroll
    for (int k = 0; k < 2; ++k) {            // 1024 (o, c-pair) items
        int i = t + k * 512;
        int o = i & 31;                       // coalesced filt reads
        int cp = i >> 5;                      // 0..31 (c = 2cp, 2cp+1)
        int g0 = (2 * cp) * 128 + obase + o;
        int g1 = g0 + 128;
        unsigned wd = o * 32 + (((cp >> 2) ^ (o & 7)) << 2) + (cp & 3); // swizzled dword
        #pragma unroll
        for (int b = 0; b < 3; ++b) {
            float f0a = filt[b * 8192 + g0],       f0b = filt[b * 8192 + g1];
            float f1a = filt[(3 + b) * 8192 + g0], f1b = filt[(3 + b) * 8192 + g1];
            float f2a = filt[(6 + b) * 8192 + g0], f2b = filt[(6 + b) * 8192 + g1];
            float Pa = fmaf(cu2, f2a, fmaf(cu1, f1a, f0a));
            float Pb = fmaf(cu2, f2b, fmaf(cu1, f1b, f0b));
            pq32[b * 1024 + wd] = pack2(Pa, Pb);
            if (b > 0) {
                float Qa = fmaf(su2, f2a, su1 * f1a);
                float Qb = fmaf(su2, f2b, su1 * f1b);
                pq32[(b + 2) * 1024 + wd] = pack2(Qa, Qb);
            }
        }
    }

    // ---- wave assignment
    const int wave = t >> 6;
    const int lane = t & 63;
    const int vg   = wave >> 1;       // 2 v's per wave: vloc = vg*2 + j
    const int nth  = wave & 1;        // THE o-tile (32 o = 2 tiles)
    const int ln15 = lane & 15;
    const int q    = lane >> 4;
    const int swz  = ln15 & 7;
    const int part = q >> 1;
    const int nbase = (q & 1) * 4;

    const int sxv = t >> 6;           // staging: chunk-local v (0..7)
    const int nh  = (t >> 5) & 1;     // staging: n-half
    const int scp = t & 31;           // staging: c-pair

    float ssum = 0.f, ssq = 0.f;

    #pragma unroll 1
    for (int chk = 0; chk < 8; ++chk) {
        // ---- stage x' chunk of 8 v (same pattern as verified 16-v staging)
        {
            const int vglob = vbase0 + chk * 8 + sxv;
            #pragma unroll
            for (int k = 0; k < 4; ++k) {
                int n = nh * 4 + k;
                size_t gi = (((size_t)(n * 128 + u)) * 128 + vglob) * 64 + 2 * scp;
                float2 r  = *(const float2*)(xr + gi);
                float2 m2 = *(const float2*)(xi + gi);
                unsigned rp = pack2(r.x + m2.x, r.y + m2.y);
                unsigned ip = pack2(m2.x - r.x, m2.y - r.y);
                unsigned base = (sxv * 16 + n) * 32 + (((scp >> 2) ^ (n & 7)) << 2) + (scp & 3);
                xs32[base] = rp;               // np = n      (r+i)
                xs32[base + 256] = ip;         // np = 8+n    (i-r)
            }
        }
        __syncthreads();

        // ---- per-v trig (2 v's per wave)
        float cv1[2], cv2[2], nsv1[2], nsv2[2];
        #pragma unroll
        for (int j = 0; j < 2; ++j) {
            float av = 6.28318530717958647692f *
                       (float)(vbase0 + chk * 8 + vg * 2 + j) / 128.0f;
            float s1, c1, s2, c2;
            __sincosf(av, &s1, &c1);
            __sincosf(2.0f * av, &s2, &c2);
            cv1[j] = c1; cv2[j] = c2; nsv1[j] = -s1; nsv2[j] = -s2;
        }

        // ---- A-fragments (swizzled b128, layout == MFMA A order)
        bf16x8 af[2][2];
        #pragma unroll
        for (int j = 0; j < 2; ++j) {
            const unsigned short* xrow = &xsh[((vg * 2 + j) * 16 + ln15) * 64];
            #pragma unroll
            for (int ks = 0; ks < 2; ++ks) {
                int m = ks * 4 + q;
                af[j][ks] = __builtin_bit_cast(bf16x8,
                    *(const uint4*)(xrow + ((m ^ swz) << 3)));
            }
        }

        // ---- main: unpack planes once per ks, synth kr per v (v2-verified math)
        const int o_loc = nth * 16 + ln15;
        const unsigned short* prow = &pqT[o_loc * 64];
        f32x4 acc[2];
        acc[0] = (f32x4){0.f, 0.f, 0.f, 0.f};
        acc[1] = (f32x4){0.f, 0.f, 0.f, 0.f};

        #pragma unroll
        for (int ks = 0; ks < 2; ++ks) {
            const int m = ks * 4 + q;
            const int foff = (m ^ swz) << 3;     // (o_loc&7)==ln15&7==swz
            float P0[8], P1[8], P2[8], Q1[8], Q2[8];
            unpack8(*(const uint4*)(prow + 0 * 2048 + foff), P0);
            unpack8(*(const uint4*)(prow + 1 * 2048 + foff), P1);
            unpack8(*(const uint4*)(prow + 2 * 2048 + foff), P2);
            unpack8(*(const uint4*)(prow + 3 * 2048 + foff), Q1);
            unpack8(*(const uint4*)(prow + 4 * 2048 + foff), Q2);
            #pragma unroll
            for (int j = 0; j < 2; ++j) {
                float kr[8];
                #pragma unroll
                for (int jj = 0; jj < 8; ++jj) {
                    float tv = fmaf(cv1[j], P1[jj], P0[jj]);
                    tv = fmaf(cv2[j], P2[jj], tv);
                    tv = fmaf(nsv1[j], Q1[jj], tv);
                    kr[jj] = fmaf(nsv2[j], Q2[jj], tv);
                }
                uint4 B;
                B.x = pack2(kr[0], kr[1]); B.y = pack2(kr[2], kr[3]);
                B.z = pack2(kr[4], kr[5]); B.w = pack2(kr[6], kr[7]);
                acc[j] = __builtin_amdgcn_mfma_f32_16x16x32_bf16(
                    af[j][ks], __builtin_bit_cast(bf16x8, B), acc[j], 0, 0, 0);
            }
        }

        // ---- store + stats (cached stores: out re-read in phase 3 via L2/L3)
        const int o_glob = obase + o_loc;
        #pragma unroll
        for (int j = 0; j < 2; ++j) {
            const int vglob = vbase0 + chk * 8 + vg * 2 + j;
            size_t base = (size_t)part * 16777216 + (size_t)nbase * 2097152
                        + ((size_t)(u * 128 + vglob)) * 128 + o_glob;
            #pragma unroll
            for (int r = 0; r < 4; ++r) {
                float y = acc[j][r];
                out[base + (size_t)r * 2097152] = y;
                ssum += y;
                ssq = fmaf(y, y, ssq);
            }
        }
        __syncthreads();    // xsh fully consumed before next chunk's staging
    }

    // ---- block-level stats reduction -> global atomics (device scope)
    statl[t] = 0.f;
    __syncthreads();
    {
        int chn = part * 128 + obase + nth * 16 + ln15;
        atomicAdd(&statl[chn], ssum);
        atomicAdd(&statl[256 + chn], ssq);
    }
    __syncthreads();
    atomicAdd(&gstats[t], statl[t]);

    // ================= grid-wide spin barrier (all 1024 blocks resident) ========
    __syncthreads();                       // all block's gstats atomics retired
    if (t == 0) {
        __threadfence();
        atomicAdd(done, 1u);
        while (atomicAdd(done, 0u) < 1024u) {
            __builtin_amdgcn_s_sleep(2);
        }
        __threadfence();
    }
    __syncthreads();

    // ---- phase 2: all 256 channels' scale/shift into LDS (coherent atomic reads)
    if (t < 256) {
        int pp = t >> 7, o = t & 127;
        const float inv = 1.0f / 131072.0f;
        float s0 = atomicAdd(&gstats[t], 0.0f);
        float s1 = atomicAdd(&gstats[256 + t], 0.0f);
        float mean = s0 * inv;
        float var  = s1 * inv - mean * mean;
        float g = pp ? gi[o] : gr[o];
        float b = pp ? bi[o] : br[o];
        float s = g * rsqrtf(var + 1e-3f);
        statl[t]       = s;
        statl[256 + t] = b - mean * s;
    }
    __syncthreads();

    // ---- phase 3: BN+LeakyReLU on this block's own slice, in place
    const f32x4* scv = (const f32x4*)statl;          // [64] scale vectors
    const f32x4* shv = (const f32x4*)(statl + 256);  // [64] shift vectors
    const int ob4 = obase >> 2;
    #pragma unroll 4
    for (int it2 = 0; it2 < 16; ++it2) {
        int idx = t + it2 * 512;           // 0..8191 over [part][n][v][o/4]
        int oq4 = idx & 7;                 // 8 o-quads = 32 o
        int vv = (idx >> 3) & 63;
        int nn = (idx >> 9) & 7;
        int pp = idx >> 12;
        size_t e = ((((size_t)(pp * 8 + nn) * 128 + u) * 128
                   + (size_t)(vbase0 + vv)) << 7) + (size_t)(obase + oq4 * 4);
        f32x4 x = *(const f32x4*)(out + e);
        f32x4 sc = scv[pp * 32 + ob4 + oq4];
        f32x4 sh = shv[pp * 32 + ob4 + oq4];
        f32x4 y;
        #pragma unroll
        for (int r = 0; r < 4; ++r) {
            float w = fmaf(x[r], sc[r], sh[r]);
            y[r] = w >= 0.0f ? w : 0.2f * w;
        }
        __builtin_nontemporal_store(y, (f32x4*)(out + e));
    }
}

extern "C" void kernel_launch(void* const* d_in, const int* in_sizes, int n_in,
                              void* d_out, int out_size, void* d_ws, size_t ws_size,
                              hipStream_t stream)
{
    const float* xr   = (const float*)d_in[0];
    const float* xi   = (const float*)d_in[1];
    const float* filt = (const float*)d_in[2];
    const float* gr   = (const float*)d_in[3];
    const float* br   = (const float*)d_in[4];
    const float* gi   = (const float*)d_in[5];
    const float* bi   = (const float*)d_in[6];
    float* out = (float*)d_out;
    float* ws  = (float*)d_ws;

    float* gstats  = ws;                    // 512 floats
    unsigned* done = (unsigned*)(ws + 512); // 1 uint

    (void)hipMemsetAsync(ws, 0, 516 * sizeof(float), stream);
    conv_bn_fused<<<dim3(1024), dim3(512), 0, stream>>>(
        xr, xi, filt, out, gstats, done, gr, br, gi, bi);
}